// Round 14
// baseline (8566.848 us; speedup 1.0000x reference)
//
#include <hip/hip_runtime.h>
#include <hip/hip_bf16.h>
#include <stdint.h>

#define LSEQ   16384
#define BATCH  32
#define HIDN   32
#define NGATE  128   // 4*HIDN
#define INDIM  64

typedef float v2f __attribute__((ext_vector_type(2)));
typedef int   v2i __attribute__((ext_vector_type(2)));

// libm-accurate sigmoid for the small output kernels.
__device__ __forceinline__ float fsig(float x) { return 1.f / (1.f + expf(-x)); }

__device__ __forceinline__ float readlane_f(float v, int l) {
    return __uint_as_float((unsigned)__builtin_amdgcn_readlane((int)__float_as_uint(v), l));
}

// lane l<32 gets x from lane l+32; lanes >=32 get their own x (unused there).
// v_permlane32_swap_b32 semantics: vdst[32:63] <-> vsrc[0:31]. With both
// operands = x, ret.y (new src) has: lanes 0-31 = hi-half value; 32-63 = own.
__device__ __forceinline__ float xswap32(float x) {
    v2i r = __builtin_amdgcn_permlane32_swap(
        (int)__float_as_uint(x), (int)__float_as_uint(x), false, false);
    return __uint_as_float((unsigned)r.y);
}

// ---------------------------------------------------------------------------
// k_prep: bias2[d][j] = bih[j] + bhh[j]; zero hsum (fp64) and h/c state.
// ---------------------------------------------------------------------------
__global__ __launch_bounds__(256) void k_prep(
    const float* __restrict__ bih_f, const float* __restrict__ bhh_f,
    const float* __restrict__ bih_b, const float* __restrict__ bhh_b,
    float* __restrict__ bias2, double* __restrict__ hsum, float* __restrict__ state)
{
    int gid = blockIdx.x * 256 + threadIdx.x;   // [0, 4096)
    if (gid < 256) {
        int dd = gid >> 7, jj = gid & 127;
        float bi = dd ? bih_b[jj] : bih_f[jj];
        float bh = dd ? bhh_b[jj] : bhh_f[jj];
        bias2[gid] = __fadd_rn(bi, bh);
    }
    if (gid < 2 * BATCH * HIDN) hsum[gid] = 0.0;
    state[gid] = 0.f;   // 4096 = 2*B*2*32
}

// ---------------------------------------------------------------------------
// gx device body: exact (fp64) dots rounded to fp32 where numpy rounds.
// BIT-IDENTICAL to the R8-passing k_gx. Store layout:
//   out2[k]    = (i_k, f_k)     k in [0,32)
//   out2[32+k] = (g_k, o_k)
// ---------------------------------------------------------------------------
__device__ __forceinline__ void gx_device(
    const float* __restrict__ features,  // [B][64][L]
    const float* __restrict__ proj_W,    // [32][64]
    const float* __restrict__ proj_b,    // [32]
    const float* __restrict__ Wih_f,     // [128][32]
    const float* __restrict__ Wih_b,
    const float* __restrict__ bias2,     // [2][128]
    float* __restrict__ gx,
    int chunkT, int s0, int blk, int tid)
{
    int tilesPerB = chunkT >> 8;
    int b  = blk / tilesPerB;
    int tt = (blk % tilesPerB) * 256 + tid;
    int s  = s0 + tt;

    #pragma unroll 1
    for (int d = 0; d < 2; ++d) {
        int t = d ? (LSEQ - 1 - s) : s;
        float f[INDIM];
        #pragma unroll
        for (int k = 0; k < INDIM; ++k)
            f[k] = features[((size_t)b * INDIM + k) * LSEQ + t];

        float proj[HIDN];
        #pragma unroll 1
        for (int m = 0; m < HIDN; ++m) {
            double sA = 0.0, sB = 0.0, sC = 0.0, sD = 0.0;
            #pragma unroll
            for (int k = 0; k < INDIM; k += 4) {
                sA += (double)proj_W[m * INDIM + k + 0] * (double)f[k + 0];
                sB += (double)proj_W[m * INDIM + k + 1] * (double)f[k + 1];
                sC += (double)proj_W[m * INDIM + k + 2] * (double)f[k + 2];
                sD += (double)proj_W[m * INDIM + k + 3] * (double)f[k + 3];
            }
            proj[m] = (float)(((double)proj_b[m] + sA + sB) + (sC + sD));
        }

        const float* Wih = d ? Wih_b : Wih_f;
        const float* bs  = bias2 + d * NGATE;
        float2* out2 = (float2*)(gx + (((size_t)(d * BATCH + b) * chunkT + tt) << 7));
        #pragma unroll 1
        for (int kq = 0; kq < HIDN; ++kq) {
            const float* Wi = Wih + (kq)      * HIDN;
            const float* Wf = Wih + (kq + 32) * HIDN;
            const float* Wg = Wih + (kq + 64) * HIDN;
            const float* Wo = Wih + (kq + 96) * HIDN;
            double si_e = 0, si_o = 0, sf_e = 0, sf_o = 0;
            double sg_e = 0, sg_o = 0, so_e = 0, so_o = 0;
            #pragma unroll
            for (int m = 0; m < HIDN; m += 2) {
                double pe = (double)proj[m], po = (double)proj[m + 1];
                si_e += (double)Wi[m] * pe;  si_o += (double)Wi[m + 1] * po;
                sf_e += (double)Wf[m] * pe;  sf_o += (double)Wf[m + 1] * po;
                sg_e += (double)Wg[m] * pe;  sg_o += (double)Wg[m + 1] * po;
                so_e += (double)Wo[m] * pe;  so_o += (double)Wo[m + 1] * po;
            }
            float2 vif, vgo;
            vif.x = (float)(((double)bs[kq]      + si_e) + si_o);
            vif.y = (float)(((double)bs[kq + 32] + sf_e) + sf_o);
            vgo.x = (float)(((double)bs[kq + 64] + sg_e) + sg_o);
            vgo.y = (float)(((double)bs[kq + 96] + so_e) + so_o);
            out2[kq]      = vif;
            out2[32 + kq] = vgo;
        }
    }
}

__global__ __launch_bounds__(256) void k_gx(
    const float* __restrict__ features, const float* __restrict__ proj_W,
    const float* __restrict__ proj_b, const float* __restrict__ Wih_f,
    const float* __restrict__ Wih_b, const float* __restrict__ bias2,
    float* __restrict__ gx, int chunkT, int s0)
{
    gx_device(features, proj_W, proj_b, Wih_f, Wih_b, bias2, gx,
              chunkT, s0, blockIdx.x, threadIdx.x);
}

// ---------------------------------------------------------------------------
// One interleaved step of TWO independent LSTMs (pairs A and B, same dir).
// Each pair's dataflow is BITWISE identical to R13's LSTM_STEP (sequential
// m=0..31 pk-fma chain, __expf + IEEE div, numpy c/h rounding); the two
// independent streams are alternated so B's instructions fill A's latency
// stalls (in-order single-wave issue).
// ---------------------------------------------------------------------------
template<int HSTEP>
__device__ __forceinline__ void lstm_step2(
    float2 cvA, float2 cvB, int idx,
    v2f (&wv)[HIDN], float qq, float nn, float aa,
    float& hcurA, float& cA, double& hsA, float* hpA,
    float& hcurB, float& cB, double& hsB, float* hpB)
{
    v2f accA = v2f{cvA.x, cvA.y};
    v2f accB = v2f{cvB.x, cvB.y};
    #pragma unroll
    for (int m = 0; m < HIDN; ++m) {
        float hmA = readlane_f(hcurA, m);
        float hmB = readlane_f(hcurB, m);
        accA = __builtin_elementwise_fma(wv[m], v2f{hmA, hmA}, accA);
        accB = __builtin_elementwise_fma(wv[m], v2f{hmB, hmB}, accB);
    }
    float g0A = accA.x, g1A = accA.y;
    float g0B = accB.x, g1B = accB.y;
    float e0A = __expf(qq * g0A);
    float e0B = __expf(qq * g0B);
    float a0A = nn / (1.f + e0A) + aa;
    float a0B = nn / (1.f + e0B) + aa;
    float e1A = __expf(-g1A);
    float e1B = __expf(-g1B);
    float a1A = 1.f / (1.f + e1A);
    float a1B = 1.f / (1.f + e1B);
    float xgA = xswap32(a0A);
    float xgB = xswap32(a0B);
    float xoA = xswap32(a1A);
    float xoB = xswap32(a1B);
    float cnA = __fadd_rn(__fmul_rn(a1A, cA), __fmul_rn(a0A, xgA));
    float cnB = __fadd_rn(__fmul_rn(a1B, cB), __fmul_rn(a0B, xgB));
    float ecA = __expf(-2.f * cnA);
    float ecB = __expf(-2.f * cnB);
    float tcA = 2.f / (1.f + ecA) - 1.f;
    float tcB = 2.f / (1.f + ecB) - 1.f;
    float hnA = __fmul_rn(xoA, tcA);
    float hnB = __fmul_rn(xoB, tcB);
    cA = cnA; hcurA = hnA; hsA += (double)hnA;
    cB = cnB; hcurB = hnB; hsB += (double)hnB;
    hpA[idx * HSTEP * HIDN] = hnA;
    hpB[idx * HSTEP * HIDN] = hnB;
}

// Main dual-pair recurrence loop; direction templated (immediate offsets).
// Ping-pong prefetch per pair (distance 8). hp for lanes>=32 -> trash.
template<int HSTEP>
__device__ __forceinline__ void rec_body2(
    const float2* __restrict__ gqA, const float2* __restrict__ gqB,
    float* __restrict__ hpA, float* __restrict__ hpB,
    v2f (&wv)[HIDN], float qq, float nn, float aa,
    float& hcurA, float& cA, double& hsA,
    float& hcurB, float& cB, double& hsB,
    int chunkT, int lane)
{
    const ptrdiff_t adv = (lane < HIDN) ? (ptrdiff_t)16 * HSTEP * HIDN : 0;

    float2 PA[8], QA[8], PB[8], QB[8];
    #pragma unroll
    for (int u = 0; u < 8; ++u) {
        PA[u] = gqA[u * 64 + lane];
        PB[u] = gqB[u * 64 + lane];
    }

    #pragma unroll 1
    for (int tt = 0; tt < chunkT; tt += 16) {
        #pragma unroll
        for (int u = 0; u < 8; ++u) {
            QA[u] = gqA[(u + 8) * 64 + lane];
            QB[u] = gqB[(u + 8) * 64 + lane];
            lstm_step2<HSTEP>(PA[u], PB[u], u, wv, qq, nn, aa,
                              hcurA, cA, hsA, hpA, hcurB, cB, hsB, hpB);
        }
        #pragma unroll
        for (int u = 0; u < 8; ++u) {
            PA[u] = gqA[(u + 16) * 64 + lane];   // pad covers tail overread
            PB[u] = gqB[(u + 16) * 64 + lane];
            lstm_step2<HSTEP>(QA[u], QB[u], 8 + u, wv, qq, nn, aa,
                              hcurA, cA, hsA, hpA, hcurB, cB, hsB, hpB);
        }
        gqA += 16 * 64; gqB += 16 * 64;
        hpA += adv;     hpB += adv;
    }
}

// ---------------------------------------------------------------------------
// k_fused: blocks 0..31 = dual-pair recurrence (1 wave each; pairs (d,b) and
// (d,b+16) share Whh); blocks 32+ = gx for the NEXT chunk into gxDst.
// ---------------------------------------------------------------------------
__global__ __launch_bounds__(256)
__attribute__((amdgpu_waves_per_eu(1)))
void k_fused(
    const float* __restrict__ gxSrc,   // [2][B][chunkT][64 float2] (+pad)
    float* __restrict__ gxDst,
    const float* __restrict__ features, const float* __restrict__ proj_W,
    const float* __restrict__ proj_b, const float* __restrict__ Wih_f,
    const float* __restrict__ Wih_b, const float* __restrict__ bias2,
    const float* __restrict__ Whh_f,   // [128][32]
    const float* __restrict__ Whh_b,
    float* __restrict__ hbuf,          // [2][B][L][32] fp32
    float* __restrict__ state,         // [2][B][2][32]  (h then c)
    double* __restrict__ hsum,         // [2][B][32] fp64
    float* __restrict__ trash,         // 16 KiB dead zone (hi-lane stores)
    int chunkT, int s0_rec, int s0_gx)
{
    if (blockIdx.x >= 32) {
        gx_device(features, proj_W, proj_b, Wih_f, Wih_b, bias2, gxDst,
                  chunkT, s0_gx, blockIdx.x - 32, threadIdx.x);
        return;
    }
    if (threadIdx.x >= 64) return;
    __builtin_amdgcn_s_setprio(1);      // favor rec wave over co-resident gx waves

    const int blk  = blockIdx.x;        // [0,32): d = blk>>4, bA = blk&15
    const int d    = blk >> 4;
    const int wgA  = d * 32 + (blk & 15);
    const int wgB  = wgA + 16;
    const int lane = threadIdx.x;
    const int k    = lane & 31;
    const int half = lane >> 5;         // 0: i/f rows, 1: g/o rows
    const int r0   = k + (half << 6);   // i or g row
    const int r1   = r0 + 32;           // f or o row

    // a0 activation: lo lanes sigmoid(i), hi lanes tanh(g)
    const float qq = half ? -2.f : -1.f;
    const float nn = half ?  2.f :  1.f;
    const float aa = half ? -1.f :  0.f;

    const float* whh = d ? Whh_b : Whh_f;
    // wv[m] = (Whh[r0][m], Whh[r1][m]) — shared by both pairs (same d)
    v2f wv[HIDN];
    #pragma unroll
    for (int q = 0; q < 8; ++q) {
        float4 a = *reinterpret_cast<const float4*>(whh + r0 * HIDN + 4 * q);
        float4 b = *reinterpret_cast<const float4*>(whh + r1 * HIDN + 4 * q);
        wv[4 * q + 0] = v2f{a.x, b.x};
        wv[4 * q + 1] = v2f{a.y, b.y};
        wv[4 * q + 2] = v2f{a.z, b.z};
        wv[4 * q + 3] = v2f{a.w, b.w};
    }

    float* stA = state + (wgA << 6);
    float* stB = state + (wgB << 6);
    float hcurA = stA[k],        hcurB = stB[k];
    float cA    = stA[HIDN + k], cB    = stB[HIDN + k];
    double hsA = (lane < HIDN) ? hsum[wgA * HIDN + lane] : 0.0;
    double hsB = (lane < HIDN) ? hsum[wgB * HIDN + lane] : 0.0;

    const float2* gqA = reinterpret_cast<const float2*>(gxSrc) + ((size_t)wgA * chunkT << 6);
    const float2* gqB = reinterpret_cast<const float2*>(gxSrc) + ((size_t)wgB * chunkT << 6);
    const int t0 = d ? (LSEQ - 1 - s0_rec) : s0_rec;
    float* hpAr = hbuf + (((size_t)wgA * LSEQ + t0) << 5) + k;
    float* hpBr = hbuf + (((size_t)wgB * LSEQ + t0) << 5) + k;
    float* hpA = (lane < HIDN) ? hpAr : (trash + 1024 + lane);
    float* hpB = (lane < HIDN) ? hpBr : (trash + 1024 + 128 + lane);

    if (d == 0)
        rec_body2<+1>(gqA, gqB, hpA, hpB, wv, qq, nn, aa,
                      hcurA, cA, hsA, hcurB, cB, hsB, chunkT, lane);
    else
        rec_body2<-1>(gqA, gqB, hpA, hpB, wv, qq, nn, aa,
                      hcurA, cA, hsA, hcurB, cB, hsB, chunkT, lane);

    if (lane < HIDN) {
        stA[lane] = hcurA;        stB[lane] = hcurB;
        stA[HIDN + lane] = cA;    stB[HIDN + lane] = cB;
        hsum[wgA * HIDN + lane] = hsA;
        hsum[wgB * HIDN + lane] = hsB;
    }
}

// ---------------------------------------------------------------------------
// k_probs: per (b,t): h1 = relu([hf,hb] @ bc_W1.T + b1); p = sig(h1.bc_W2+b2);
//          edge *1.2; clip [0,1]. fp64 dots, 2-way chain split.
// ---------------------------------------------------------------------------
__global__ __launch_bounds__(256) void k_probs(
    const float* __restrict__ hbuf,            // [2][B][L][32] fp32
    const float* __restrict__ bcW1, const float* __restrict__ bcb1,
    const float* __restrict__ bcW2, const float* __restrict__ bcb2,
    float* __restrict__ out)
{
    int idx = blockIdx.x * 256 + threadIdx.x;   // b*L + t
    int t = idx & (LSEQ - 1);
    int b = idx >> 14;

    float h[64];
    const float* pf = hbuf + (((size_t)b * LSEQ + t) << 5);
    const float* pb = hbuf + (((size_t)(BATCH + b) * LSEQ + t) << 5);
    #pragma unroll
    for (int q = 0; q < 8; ++q) {
        float4 v = reinterpret_cast<const float4*>(pf)[q];
        h[q * 4] = v.x; h[q * 4 + 1] = v.y; h[q * 4 + 2] = v.z; h[q * 4 + 3] = v.w;
    }
    #pragma unroll
    for (int q = 0; q < 8; ++q) {
        float4 v = reinterpret_cast<const float4*>(pb)[q];
        h[32 + q * 4] = v.x; h[32 + q * 4 + 1] = v.y; h[32 + q * 4 + 2] = v.z; h[32 + q * 4 + 3] = v.w;
    }

    double a2 = (double)bcb2[0];
    #pragma unroll 1
    for (int m = 0; m < 32; ++m) {
        double ae = 0.0, ao = 0.0;
        #pragma unroll
        for (int kk = 0; kk < 64; kk += 2) {
            ae += (double)bcW1[m * 64 + kk]     * (double)h[kk];
            ao += (double)bcW1[m * 64 + kk + 1] * (double)h[kk + 1];
        }
        float af = fmaxf((float)(((double)bcb1[m] + ae) + ao), 0.f);
        a2 += (double)bcW2[m] * (double)af;
    }
    float p = fsig((float)a2);
    if (t == 0 || t == LSEQ - 1) p = __fmul_rn(p, 1.2f);
    p = fminf(fmaxf(p, 0.f), 1.f);
    out[idx] = p;
}

__global__ __launch_bounds__(256) void k_adj(
    const float* __restrict__ probs, float* __restrict__ adj)
{
    int idx = blockIdx.x * 256 + threadIdx.x;
    int t = idx & (LSEQ - 1);
    float a = 0.f;
    if (t > 0 && t < LSEQ - 1) {
        float p = probs[idx], pm = probs[idx - 1], pp = probs[idx + 1];
        float left = __fadd_rn(p, -pm), right = __fadd_rn(p, -pp);
        float al = fabsf(left), ar = fabsf(right);
        if (left < 0.f && al > ar)       a = -1.f;
        else if (right < 0.f && ar > al) a =  1.f;
    }
    adj[idx] = a;
}

__global__ __launch_bounds__(64) void k_realp(
    const double* __restrict__ hsum, const float* __restrict__ rcW,
    const float* __restrict__ rcb, float* __restrict__ out)
{
    int b = threadIdx.x;
    if (b < BATCH) {
        const double invL = 1.0 / (double)LSEQ;
        double acc = (double)rcb[0];
        #pragma unroll
        for (int kk = 0; kk < 32; ++kk) {
            acc += hsum[b * 32 + kk] * invL * (double)rcW[kk];
            acc += hsum[(BATCH + b) * 32 + kk] * invL * (double)rcW[32 + kk];
        }
        out[b] = fsig((float)acc);
    }
}

// ---------------------------------------------------------------------------
extern "C" void kernel_launch(void* const* d_in, const int* in_sizes, int n_in,
                              void* d_out, int out_size, void* d_ws, size_t ws_size,
                              hipStream_t stream)
{
    (void)in_sizes; (void)n_in; (void)out_size;
    const float* features = (const float*)d_in[0];
    const float* proj_W   = (const float*)d_in[1];
    const float* proj_b   = (const float*)d_in[2];
    const float* Wih_f    = (const float*)d_in[3];
    const float* Whh_f    = (const float*)d_in[4];
    const float* bih_f    = (const float*)d_in[5];
    const float* bhh_f    = (const float*)d_in[6];
    const float* Wih_b    = (const float*)d_in[7];
    const float* Whh_b    = (const float*)d_in[8];
    const float* bih_b    = (const float*)d_in[9];
    const float* bhh_b    = (const float*)d_in[10];
    const float* bcW1     = (const float*)d_in[11];
    const float* bcb1     = (const float*)d_in[12];
    const float* bcW2     = (const float*)d_in[13];
    const float* bcb2     = (const float*)d_in[14];
    const float* rcW      = (const float*)d_in[15];
    const float* rcb      = (const float*)d_in[16];

    char* ws = (char*)d_ws;
    float*  bias2 = (float*)(ws + 65536);              // 1 KiB
    double* hsum  = (double*)(ws + 66560);             // 16 KiB (fp64)
    float*  state = (float*)(ws + 82944);              // 16 KiB
    float*  trash = (float*)(ws + 102400);             // 16 KiB dead zone
    const size_t HBYTES = (size_t)2 * BATCH * LSEQ * HIDN * sizeof(float); // 128 MiB
    float* hbuf = (float*)(ws + (1u << 20));
    const size_t GXOFF = (1u << 20) + HBYTES;

    // chunkT selection: largest pow2 whose DOUBLE-buffered gx fits (pipelined
    // mode); else single-buffer serial fallback. Deterministic from ws_size.
    auto gxstride = [](int c) { return (size_t)c * 32768 + 16384; };
    int chunkT = LSEQ;
    bool dbuf = true;
    while (chunkT > 256 && GXOFF + 2 * gxstride(chunkT) > ws_size) chunkT >>= 1;
    if (GXOFF + 2 * gxstride(chunkT) > ws_size) {
        dbuf = false;
        chunkT = LSEQ;
        while (chunkT > 256 && GXOFF + gxstride(chunkT) > ws_size) chunkT >>= 1;
    }
    const int nch = LSEQ / chunkT;
    float* gx0 = (float*)(ws + GXOFF);
    float* gx1 = dbuf ? (float*)(ws + GXOFF + gxstride(chunkT)) : gx0;

    float* outp = (float*)d_out;
    const int BL = BATCH * LSEQ;
    const int gxblocks = BATCH * (chunkT >> 8);

    k_prep<<<16, 256, 0, stream>>>(bih_f, bhh_f, bih_b, bhh_b, bias2, hsum, state);
    k_gx<<<gxblocks, 256, 0, stream>>>(features, proj_W, proj_b,
                                       Wih_f, Wih_b, bias2, gx0, chunkT, 0);
    for (int c = 0; c < nch; ++c) {
        float* src = (c & 1) ? gx1 : gx0;
        float* dst = (c & 1) ? gx0 : gx1;
        if (dbuf) {
            bool more = (c + 1 < nch);
            k_fused<<<32 + (more ? gxblocks : 0), 256, 0, stream>>>(
                src, dst, features, proj_W, proj_b, Wih_f, Wih_b, bias2,
                Whh_f, Whh_b, hbuf, state, hsum, trash,
                chunkT, c * chunkT, (c + 1) * chunkT);
        } else {
            if (c > 0)
                k_gx<<<gxblocks, 256, 0, stream>>>(features, proj_W, proj_b,
                                                   Wih_f, Wih_b, bias2, gx0,
                                                   chunkT, c * chunkT);
            k_fused<<<32, 256, 0, stream>>>(
                gx0, gx0, features, proj_W, proj_b, Wih_f, Wih_b, bias2,
                Whh_f, Whh_b, hbuf, state, hsum, trash,
                chunkT, c * chunkT, 0);
        }
    }
    k_probs<<<BL / 256, 256, 0, stream>>>(hbuf, bcW1, bcb1, bcW2, bcb2, outp);
    k_adj<<<BL / 256, 256, 0, stream>>>(outp, outp + BL);
    k_realp<<<1, 64, 0, stream>>>(hsum, rcW, rcb, outp + 2 * BL);
}

// Round 16
// 8371.664 us; speedup vs baseline: 1.0233x; 1.0233x over previous
//
#include <hip/hip_runtime.h>
#include <hip/hip_bf16.h>
#include <stdint.h>

#define LSEQ   16384
#define BATCH  32
#define HIDN   32
#define NGATE  128   // 4*HIDN
#define INDIM  64

typedef float v2f __attribute__((ext_vector_type(2)));
typedef int   v2i __attribute__((ext_vector_type(2)));

// libm-accurate sigmoid for the small output kernels.
__device__ __forceinline__ float fsig(float x) { return 1.f / (1.f + expf(-x)); }

__device__ __forceinline__ float readlane_f(float v, int l) {
    return __uint_as_float((unsigned)__builtin_amdgcn_readlane((int)__float_as_uint(v), l));
}

// Full-exec half-swap: every lane l receives v[l^32].
// MUST be called unconditionally in uniform control flow (R15 lesson: a
// permlane under a divergent ternary runs with half-exec and fi=false leaves
// the cross-half read unfetched -> lanes silently keep their own value).
// v_permlane32_swap_b32(dst,src): dst[32:63] <-> src[0:31]. With dst=src=v:
//   ret.x lane l>=32 = v[l-32];  ret.y lane l<32 = v[l+32].
__device__ __forceinline__ float halfswap(float v, bool lo) {
    v2i r = __builtin_amdgcn_permlane32_swap(
        (int)__float_as_uint(v), (int)__float_as_uint(v), false, false);
    return __uint_as_float((unsigned)(lo ? r.y : r.x));
}

// ---------------------------------------------------------------------------
// k_prep: bias2[d][j] = bih[j] + bhh[j]; zero hsum (fp64) and h/c state.
// ---------------------------------------------------------------------------
__global__ __launch_bounds__(256) void k_prep(
    const float* __restrict__ bih_f, const float* __restrict__ bhh_f,
    const float* __restrict__ bih_b, const float* __restrict__ bhh_b,
    float* __restrict__ bias2, double* __restrict__ hsum, float* __restrict__ state)
{
    int gid = blockIdx.x * 256 + threadIdx.x;   // [0, 4096)
    if (gid < 256) {
        int dd = gid >> 7, jj = gid & 127;
        float bi = dd ? bih_b[jj] : bih_f[jj];
        float bh = dd ? bhh_b[jj] : bhh_f[jj];
        bias2[gid] = __fadd_rn(bi, bh);
    }
    if (gid < 2 * BATCH * HIDN) hsum[gid] = 0.0;
    state[gid] = 0.f;   // 4096 = 2*B*2*32
}

// ---------------------------------------------------------------------------
// gx device body: exact (fp64) dots rounded to fp32 where numpy rounds.
// BIT-IDENTICAL to the R8-passing k_gx. Store layout:
//   out2[k]    = (i_k, f_k)     k in [0,32)
//   out2[32+k] = (g_k, o_k)
// ---------------------------------------------------------------------------
__device__ __forceinline__ void gx_device(
    const float* __restrict__ features,  // [B][64][L]
    const float* __restrict__ proj_W,    // [32][64]
    const float* __restrict__ proj_b,    // [32]
    const float* __restrict__ Wih_f,     // [128][32]
    const float* __restrict__ Wih_b,
    const float* __restrict__ bias2,     // [2][128]
    float* __restrict__ gx,
    int chunkT, int s0, int blk, int tid)
{
    int tilesPerB = chunkT >> 8;
    int b  = blk / tilesPerB;
    int tt = (blk % tilesPerB) * 256 + tid;
    int s  = s0 + tt;

    #pragma unroll 1
    for (int d = 0; d < 2; ++d) {
        int t = d ? (LSEQ - 1 - s) : s;
        float f[INDIM];
        #pragma unroll
        for (int k = 0; k < INDIM; ++k)
            f[k] = features[((size_t)b * INDIM + k) * LSEQ + t];

        float proj[HIDN];
        #pragma unroll 1
        for (int m = 0; m < HIDN; ++m) {
            double sA = 0.0, sB = 0.0, sC = 0.0, sD = 0.0;
            #pragma unroll
            for (int k = 0; k < INDIM; k += 4) {
                sA += (double)proj_W[m * INDIM + k + 0] * (double)f[k + 0];
                sB += (double)proj_W[m * INDIM + k + 1] * (double)f[k + 1];
                sC += (double)proj_W[m * INDIM + k + 2] * (double)f[k + 2];
                sD += (double)proj_W[m * INDIM + k + 3] * (double)f[k + 3];
            }
            proj[m] = (float)(((double)proj_b[m] + sA + sB) + (sC + sD));
        }

        const float* Wih = d ? Wih_b : Wih_f;
        const float* bs  = bias2 + d * NGATE;
        float2* out2 = (float2*)(gx + (((size_t)(d * BATCH + b) * chunkT + tt) << 7));
        #pragma unroll 1
        for (int kq = 0; kq < HIDN; ++kq) {
            const float* Wi = Wih + (kq)      * HIDN;
            const float* Wf = Wih + (kq + 32) * HIDN;
            const float* Wg = Wih + (kq + 64) * HIDN;
            const float* Wo = Wih + (kq + 96) * HIDN;
            double si_e = 0, si_o = 0, sf_e = 0, sf_o = 0;
            double sg_e = 0, sg_o = 0, so_e = 0, so_o = 0;
            #pragma unroll
            for (int m = 0; m < HIDN; m += 2) {
                double pe = (double)proj[m], po = (double)proj[m + 1];
                si_e += (double)Wi[m] * pe;  si_o += (double)Wi[m + 1] * po;
                sf_e += (double)Wf[m] * pe;  sf_o += (double)Wf[m + 1] * po;
                sg_e += (double)Wg[m] * pe;  sg_o += (double)Wg[m + 1] * po;
                so_e += (double)Wo[m] * pe;  so_o += (double)Wo[m + 1] * po;
            }
            float2 vif, vgo;
            vif.x = (float)(((double)bs[kq]      + si_e) + si_o);
            vif.y = (float)(((double)bs[kq + 32] + sf_e) + sf_o);
            vgo.x = (float)(((double)bs[kq + 64] + sg_e) + sg_o);
            vgo.y = (float)(((double)bs[kq + 96] + so_e) + so_o);
            out2[kq]      = vif;
            out2[32 + kq] = vgo;
        }
    }
}

__global__ __launch_bounds__(256) void k_gx(
    const float* __restrict__ features, const float* __restrict__ proj_W,
    const float* __restrict__ proj_b, const float* __restrict__ Wih_f,
    const float* __restrict__ Wih_b, const float* __restrict__ bias2,
    float* __restrict__ gx, int chunkT, int s0)
{
    gx_device(features, proj_W, proj_b, Wih_f, Wih_b, bias2, gx,
              chunkT, s0, blockIdx.x, threadIdx.x);
}

// ---------------------------------------------------------------------------
// Lane-packed dual-pair step. Pair A state on lanes 0-31, pair B on 32-63.
// B reads its gx/Whh rows with lane^32 so its (i,f) gates land on hi lanes.
// Front (matvec + gate activations) is per-pair (bitwise = R13); the back-end
// (cn -> exp -> div -> tanh -> hn, store, hsum) is ONE shared packed stream.
// Swaps: value-select FIRST (cndmask, full exec), then ONE unconditional
// permlane32_swap, then select the return half — never under divergence.
// ---------------------------------------------------------------------------
template<int HSTEP>
__device__ __forceinline__ void step_pk(
    float2 cvA, float2 cvB, int idx,
    v2f (&wvA)[HIDN], v2f (&wvB)[HIDN],
    float qqA, float nnA, float aaA,
    float qqB, float nnB, float aaB,
    bool lo,
    float& hcur, float& c_pk, double& hs, float* hp)
{
    v2f accA = v2f{cvA.x, cvA.y};
    v2f accB = v2f{cvB.x, cvB.y};
    #pragma unroll
    for (int m = 0; m < HIDN; ++m) {
        float hmA = readlane_f(hcur, m);        // A's h lives on lanes 0-31
        float hmB = readlane_f(hcur, m + 32);   // B's h lives on lanes 32-63
        accA = __builtin_elementwise_fma(wvA[m], v2f{hmA, hmA}, accA);
        accB = __builtin_elementwise_fma(wvB[m], v2f{hmB, hmB}, accB);
    }
    // front activations (per pair, bitwise = R13)
    float e0A = __expf(qqA * accA.x);
    float e0B = __expf(qqB * accB.x);
    float a0A = nnA / (1.f + e0A) + aaA;
    float a0B = nnB / (1.f + e0B) + aaB;
    float e1A = __expf(-accA.y);
    float e1B = __expf(-accB.y);
    float a1A = 1.f / (1.f + e1A);
    float a1B = 1.f / (1.f + e1B);
    // pack: lo lanes = pair A, hi lanes = pair B.
    // vg: lo = tanh(g_B), hi = tanh(g_A)  ->  halfswap gives each lane the
    // OTHER half: lo <- tanh(g_A), hi <- tanh(g_B). Same for vo with sig(o).
    float vg  = lo ? a0B : a0A;
    float vo  = lo ? a1B : a1A;
    float xg  = halfswap(vg, lo);
    float xo  = halfswap(vo, lo);
    float a0p = lo ? a0A : a0B;                    // sig(i)
    float a1p = lo ? a1A : a1B;                    // sig(f)
    // shared packed back-end (numpy rounding pattern, bitwise = R13 per lane)
    float cn = __fadd_rn(__fmul_rn(a1p, c_pk), __fmul_rn(a0p, xg));
    float ec = __expf(-2.f * cn);
    float tc = 2.f / (1.f + ec) - 1.f;
    float hn = __fmul_rn(xo, tc);
    c_pk = cn; hcur = hn;
    hs += (double)hn;
    hp[idx * HSTEP * HIDN] = hn;                   // all 64 lanes real stores
}

// Dual-pair recurrence loop; direction templated (immediate store offsets).
// Depth-4 ping-pong prefetch per pair (keeps VGPR need ~200 incl. 128 weights).
template<int HSTEP>
__device__ __forceinline__ void rec_body2(
    const float2* __restrict__ gqA, const float2* __restrict__ gqB,
    float* __restrict__ hp,
    v2f (&wvA)[HIDN], v2f (&wvB)[HIDN],
    float qqA, float nnA, float aaA,
    float qqB, float nnB, float aaB,
    bool lo, int lane, int lxB,
    float& hcur, float& c_pk, double& hs,
    int chunkT)
{
    float2 PA[4], QA[4], PB[4], QB[4];
    #pragma unroll
    for (int u = 0; u < 4; ++u) {
        PA[u] = gqA[u * 64 + lane];
        PB[u] = gqB[u * 64 + lxB];
    }

    #pragma unroll 1
    for (int tt = 0; tt < chunkT; tt += 8) {
        #pragma unroll
        for (int u = 0; u < 4; ++u) {
            QA[u] = gqA[(u + 4) * 64 + lane];
            QB[u] = gqB[(u + 4) * 64 + lxB];
            step_pk<HSTEP>(PA[u], PB[u], u, wvA, wvB,
                           qqA, nnA, aaA, qqB, nnB, aaB, lo, hcur, c_pk, hs, hp);
        }
        #pragma unroll
        for (int u = 0; u < 4; ++u) {
            PA[u] = gqA[(u + 8) * 64 + lane];    // pad covers tail overread
            PB[u] = gqB[(u + 8) * 64 + lxB];
            step_pk<HSTEP>(QA[u], QB[u], 4 + u, wvA, wvB,
                           qqA, nnA, aaA, qqB, nnB, aaB, lo, hcur, c_pk, hs, hp);
        }
        gqA += 8 * 64; gqB += 8 * 64;
        hp  += 8 * HSTEP * HIDN;
    }
}

// ---------------------------------------------------------------------------
// k_fused: blocks 0..31 = lane-packed dual-pair recurrence (1 wave each;
// pairs (d,b) and (d,b+16)); blocks 32+ = gx for the NEXT chunk into gxDst.
// ---------------------------------------------------------------------------
__global__ __launch_bounds__(256)
__attribute__((amdgpu_waves_per_eu(1)))
void k_fused(
    const float* __restrict__ gxSrc,   // [2][B][chunkT][64 float2] (+pad)
    float* __restrict__ gxDst,
    const float* __restrict__ features, const float* __restrict__ proj_W,
    const float* __restrict__ proj_b, const float* __restrict__ Wih_f,
    const float* __restrict__ Wih_b, const float* __restrict__ bias2,
    const float* __restrict__ Whh_f,   // [128][32]
    const float* __restrict__ Whh_b,
    float* __restrict__ hbuf,          // [2][B][L][32] fp32
    float* __restrict__ state,         // [2][B][2][32]  (h then c)
    double* __restrict__ hsum,         // [2][B][32] fp64
    int chunkT, int s0_rec, int s0_gx)
{
    if (blockIdx.x >= 32) {
        gx_device(features, proj_W, proj_b, Wih_f, Wih_b, bias2, gxDst,
                  chunkT, s0_gx, blockIdx.x - 32, threadIdx.x);
        return;
    }
    if (threadIdx.x >= 64) return;
    __builtin_amdgcn_s_setprio(1);      // favor rec wave over co-resident gx waves

    const int blk  = blockIdx.x;        // [0,32): d = blk>>4, bA = blk&15
    const int d    = blk >> 4;
    const int wgA  = d * 32 + (blk & 15);
    const int wgB  = wgA + 16;
    const int lane = threadIdx.x;
    const int lxB  = lane ^ 32;
    const int k    = lane & 31;
    const int half = lane >> 5;
    const bool lo  = (half == 0);

    // A rows: lo=(i,f), hi=(g,o).  B rows flipped: lo=(g,o), hi=(i,f).
    const int r0A = k + (half << 6),       r1A = r0A + 32;
    const int r0B = k + ((half ^ 1) << 6), r1B = r0B + 32;

    // a0: A: sig(i) lo | tanh(g) hi.  B: tanh(g) lo | sig(i) hi.
    const float qqA = half ? -2.f : -1.f;
    const float nnA = half ?  2.f :  1.f;
    const float aaA = half ? -1.f :  0.f;
    const float qqB = half ? -1.f : -2.f;
    const float nnB = half ?  1.f :  2.f;
    const float aaB = half ?  0.f : -1.f;

    const float* whh = d ? Whh_b : Whh_f;
    v2f wvA[HIDN], wvB[HIDN];
    #pragma unroll
    for (int q = 0; q < 8; ++q) {
        float4 a0v = *reinterpret_cast<const float4*>(whh + r0A * HIDN + 4 * q);
        float4 a1v = *reinterpret_cast<const float4*>(whh + r1A * HIDN + 4 * q);
        float4 b0v = *reinterpret_cast<const float4*>(whh + r0B * HIDN + 4 * q);
        float4 b1v = *reinterpret_cast<const float4*>(whh + r1B * HIDN + 4 * q);
        wvA[4 * q + 0] = v2f{a0v.x, a1v.x}; wvA[4 * q + 1] = v2f{a0v.y, a1v.y};
        wvA[4 * q + 2] = v2f{a0v.z, a1v.z}; wvA[4 * q + 3] = v2f{a0v.w, a1v.w};
        wvB[4 * q + 0] = v2f{b0v.x, b1v.x}; wvB[4 * q + 1] = v2f{b0v.y, b1v.y};
        wvB[4 * q + 2] = v2f{b0v.z, b1v.z}; wvB[4 * q + 3] = v2f{b0v.w, b1v.w};
    }

    // packed state: lanes 0-31 = pair A, lanes 32-63 = pair B (index k each)
    float* stSel = state + ((lo ? wgA : wgB) << 6);
    float hcur = stSel[k];
    float c_pk = stSel[HIDN + k];
    double hs  = hsum[(lo ? wgA : wgB) * HIDN + k];

    const float2* gqA = reinterpret_cast<const float2*>(gxSrc) + ((size_t)wgA * chunkT << 6);
    const float2* gqB = reinterpret_cast<const float2*>(gxSrc) + ((size_t)wgB * chunkT << 6);
    const int t0 = d ? (LSEQ - 1 - s0_rec) : s0_rec;
    float* hp = hbuf + (((size_t)(lo ? wgA : wgB) * LSEQ + t0) << 5) + k;

    if (d == 0)
        rec_body2<+1>(gqA, gqB, hp, wvA, wvB, qqA, nnA, aaA, qqB, nnB, aaB,
                      lo, lane, lxB, hcur, c_pk, hs, chunkT);
    else
        rec_body2<-1>(gqA, gqB, hp, wvA, wvB, qqA, nnA, aaA, qqB, nnB, aaB,
                      lo, lane, lxB, hcur, c_pk, hs, chunkT);

    stSel[k] = hcur;
    stSel[HIDN + k] = c_pk;
    hsum[(lo ? wgA : wgB) * HIDN + k] = hs;
}

// ---------------------------------------------------------------------------
// k_probs: per (b,t): h1 = relu([hf,hb] @ bc_W1.T + b1); p = sig(h1.bc_W2+b2);
//          edge *1.2; clip [0,1]. fp64 dots, 2-way chain split.
// ---------------------------------------------------------------------------
__global__ __launch_bounds__(256) void k_probs(
    const float* __restrict__ hbuf,            // [2][B][L][32] fp32
    const float* __restrict__ bcW1, const float* __restrict__ bcb1,
    const float* __restrict__ bcW2, const float* __restrict__ bcb2,
    float* __restrict__ out)
{
    int idx = blockIdx.x * 256 + threadIdx.x;   // b*L + t
    int t = idx & (LSEQ - 1);
    int b = idx >> 14;

    float h[64];
    const float* pf = hbuf + (((size_t)b * LSEQ + t) << 5);
    const float* pb = hbuf + (((size_t)(BATCH + b) * LSEQ + t) << 5);
    #pragma unroll
    for (int q = 0; q < 8; ++q) {
        float4 v = reinterpret_cast<const float4*>(pf)[q];
        h[q * 4] = v.x; h[q * 4 + 1] = v.y; h[q * 4 + 2] = v.z; h[q * 4 + 3] = v.w;
    }
    #pragma unroll
    for (int q = 0; q < 8; ++q) {
        float4 v = reinterpret_cast<const float4*>(pb)[q];
        h[32 + q * 4] = v.x; h[32 + q * 4 + 1] = v.y; h[32 + q * 4 + 2] = v.z; h[32 + q * 4 + 3] = v.w;
    }

    double a2 = (double)bcb2[0];
    #pragma unroll 1
    for (int m = 0; m < 32; ++m) {
        double ae = 0.0, ao = 0.0;
        #pragma unroll
        for (int kk = 0; kk < 64; kk += 2) {
            ae += (double)bcW1[m * 64 + kk]     * (double)h[kk];
            ao += (double)bcW1[m * 64 + kk + 1] * (double)h[kk + 1];
        }
        float af = fmaxf((float)(((double)bcb1[m] + ae) + ao), 0.f);
        a2 += (double)bcW2[m] * (double)af;
    }
    float p = fsig((float)a2);
    if (t == 0 || t == LSEQ - 1) p = __fmul_rn(p, 1.2f);
    p = fminf(fmaxf(p, 0.f), 1.f);
    out[idx] = p;
}

__global__ __launch_bounds__(256) void k_adj(
    const float* __restrict__ probs, float* __restrict__ adj)
{
    int idx = blockIdx.x * 256 + threadIdx.x;
    int t = idx & (LSEQ - 1);
    float a = 0.f;
    if (t > 0 && t < LSEQ - 1) {
        float p = probs[idx], pm = probs[idx - 1], pp = probs[idx + 1];
        float left = __fadd_rn(p, -pm), right = __fadd_rn(p, -pp);
        float al = fabsf(left), ar = fabsf(right);
        if (left < 0.f && al > ar)       a = -1.f;
        else if (right < 0.f && ar > al) a =  1.f;
    }
    adj[idx] = a;
}

__global__ __launch_bounds__(64) void k_realp(
    const double* __restrict__ hsum, const float* __restrict__ rcW,
    const float* __restrict__ rcb, float* __restrict__ out)
{
    int b = threadIdx.x;
    if (b < BATCH) {
        const double invL = 1.0 / (double)LSEQ;
        double acc = (double)rcb[0];
        #pragma unroll
        for (int kk = 0; kk < 32; ++kk) {
            acc += hsum[b * 32 + kk] * invL * (double)rcW[kk];
            acc += hsum[(BATCH + b) * 32 + kk] * invL * (double)rcW[32 + kk];
        }
        out[b] = fsig((float)acc);
    }
}

// ---------------------------------------------------------------------------
extern "C" void kernel_launch(void* const* d_in, const int* in_sizes, int n_in,
                              void* d_out, int out_size, void* d_ws, size_t ws_size,
                              hipStream_t stream)
{
    (void)in_sizes; (void)n_in; (void)out_size;
    const float* features = (const float*)d_in[0];
    const float* proj_W   = (const float*)d_in[1];
    const float* proj_b   = (const float*)d_in[2];
    const float* Wih_f    = (const float*)d_in[3];
    const float* Whh_f    = (const float*)d_in[4];
    const float* bih_f    = (const float*)d_in[5];
    const float* bhh_f    = (const float*)d_in[6];
    const float* Wih_b    = (const float*)d_in[7];
    const float* Whh_b    = (const float*)d_in[8];
    const float* bih_b    = (const float*)d_in[9];
    const float* bhh_b    = (const float*)d_in[10];
    const float* bcW1     = (const float*)d_in[11];
    const float* bcb1     = (const float*)d_in[12];
    const float* bcW2     = (const float*)d_in[13];
    const float* bcb2     = (const float*)d_in[14];
    const float* rcW      = (const float*)d_in[15];
    const float* rcb      = (const float*)d_in[16];

    char* ws = (char*)d_ws;
    float*  bias2 = (float*)(ws + 65536);              // 1 KiB
    double* hsum  = (double*)(ws + 66560);             // 16 KiB (fp64)
    float*  state = (float*)(ws + 82944);              // 16 KiB
    const size_t HBYTES = (size_t)2 * BATCH * LSEQ * HIDN * sizeof(float); // 128 MiB
    float* hbuf = (float*)(ws + (1u << 20));
    const size_t GXOFF = (1u << 20) + HBYTES;

    // chunkT selection: largest pow2 whose DOUBLE-buffered gx fits (pipelined
    // mode); else single-buffer serial fallback. Deterministic from ws_size.
    auto gxstride = [](int c) { return (size_t)c * 32768 + 16384; };
    int chunkT = LSEQ;
    bool dbuf = true;
    while (chunkT > 256 && GXOFF + 2 * gxstride(chunkT) > ws_size) chunkT >>= 1;
    if (GXOFF + 2 * gxstride(chunkT) > ws_size) {
        dbuf = false;
        chunkT = LSEQ;
        while (chunkT > 256 && GXOFF + gxstride(chunkT) > ws_size) chunkT >>= 1;
    }
    const int nch = LSEQ / chunkT;
    float* gx0 = (float*)(ws + GXOFF);
    float* gx1 = dbuf ? (float*)(ws + GXOFF + gxstride(chunkT)) : gx0;

    float* outp = (float*)d_out;
    const int BL = BATCH * LSEQ;
    const int gxblocks = BATCH * (chunkT >> 8);

    k_prep<<<16, 256, 0, stream>>>(bih_f, bhh_f, bih_b, bhh_b, bias2, hsum, state);
    k_gx<<<gxblocks, 256, 0, stream>>>(features, proj_W, proj_b,
                                       Wih_f, Wih_b, bias2, gx0, chunkT, 0);
    for (int c = 0; c < nch; ++c) {
        float* src = (c & 1) ? gx1 : gx0;
        float* dst = (c & 1) ? gx0 : gx1;
        if (dbuf) {
            bool more = (c + 1 < nch);
            k_fused<<<32 + (more ? gxblocks : 0), 256, 0, stream>>>(
                src, dst, features, proj_W, proj_b, Wih_f, Wih_b, bias2,
                Whh_f, Whh_b, hbuf, state, hsum,
                chunkT, c * chunkT, (c + 1) * chunkT);
        } else {
            if (c > 0)
                k_gx<<<gxblocks, 256, 0, stream>>>(features, proj_W, proj_b,
                                                   Wih_f, Wih_b, bias2, gx0,
                                                   chunkT, c * chunkT);
            k_fused<<<32, 256, 0, stream>>>(
                gx0, gx0, features, proj_W, proj_b, Wih_f, Wih_b, bias2,
                Whh_f, Whh_b, hbuf, state, hsum,
                chunkT, c * chunkT, 0);
        }
    }
    k_probs<<<BL / 256, 256, 0, stream>>>(hbuf, bcW1, bcb1, bcW2, bcb2, outp);
    k_adj<<<BL / 256, 256, 0, stream>>>(outp, outp + BL);
    k_realp<<<1, 64, 0, stream>>>(hsum, rcW, rcb, outp + 2 * BL);
}

// Round 17
// 8308.521 us; speedup vs baseline: 1.0311x; 1.0076x over previous
//
#include <hip/hip_runtime.h>
#include <hip/hip_bf16.h>
#include <stdint.h>

#define LSEQ   16384
#define BATCH  32
#define HIDN   32
#define NGATE  128   // 4*HIDN
#define INDIM  64

typedef float v2f __attribute__((ext_vector_type(2)));
typedef int   v2i __attribute__((ext_vector_type(2)));

// libm-accurate sigmoid for the small output kernels.
__device__ __forceinline__ float fsig(float x) { return 1.f / (1.f + expf(-x)); }

__device__ __forceinline__ float readlane_f(float v, int l) {
    return __uint_as_float((unsigned)__builtin_amdgcn_readlane((int)__float_as_uint(v), l));
}

// Full-exec half-swap: every lane l receives v[l^32].
// MUST be called unconditionally in uniform control flow (R15 lesson: a
// permlane under a divergent ternary runs with half-exec and fi=false leaves
// the cross-half read unfetched -> lanes silently keep their own value).
// v_permlane32_swap_b32(dst,src): dst[32:63] <-> src[0:31]. With dst=src=v:
//   ret.x lane l>=32 = v[l-32];  ret.y lane l<32 = v[l+32].
__device__ __forceinline__ float halfswap(float v, bool lo) {
    v2i r = __builtin_amdgcn_permlane32_swap(
        (int)__float_as_uint(v), (int)__float_as_uint(v), false, false);
    return __uint_as_float((unsigned)(lo ? r.y : r.x));
}

// ---------------------------------------------------------------------------
// k_prep: bias2[d][j] = bih[j] + bhh[j]; zero hsum (fp64) and h/c state.
// ---------------------------------------------------------------------------
__global__ __launch_bounds__(256) void k_prep(
    const float* __restrict__ bih_f, const float* __restrict__ bhh_f,
    const float* __restrict__ bih_b, const float* __restrict__ bhh_b,
    float* __restrict__ bias2, double* __restrict__ hsum, float* __restrict__ state)
{
    int gid = blockIdx.x * 256 + threadIdx.x;   // [0, 4096)
    if (gid < 256) {
        int dd = gid >> 7, jj = gid & 127;
        float bi = dd ? bih_b[jj] : bih_f[jj];
        float bh = dd ? bhh_b[jj] : bhh_f[jj];
        bias2[gid] = __fadd_rn(bi, bh);
    }
    if (gid < 2 * BATCH * HIDN) hsum[gid] = 0.0;
    state[gid] = 0.f;   // 4096 = 2*B*2*32
}

// ---------------------------------------------------------------------------
// gx device body: exact (fp64) dots rounded to fp32 where numpy rounds.
// BIT-IDENTICAL to the R8-passing k_gx. Store layout:
//   out2[k]    = (i_k, f_k)     k in [0,32)
//   out2[32+k] = (g_k, o_k)
// ---------------------------------------------------------------------------
__device__ __forceinline__ void gx_device(
    const float* __restrict__ features,  // [B][64][L]
    const float* __restrict__ proj_W,    // [32][64]
    const float* __restrict__ proj_b,    // [32]
    const float* __restrict__ Wih_f,     // [128][32]
    const float* __restrict__ Wih_b,
    const float* __restrict__ bias2,     // [2][128]
    float* __restrict__ gx,
    int chunkT, int s0, int blk, int tid)
{
    int tilesPerB = chunkT >> 8;
    int b  = blk / tilesPerB;
    int tt = (blk % tilesPerB) * 256 + tid;
    int s  = s0 + tt;

    #pragma unroll 1
    for (int d = 0; d < 2; ++d) {
        int t = d ? (LSEQ - 1 - s) : s;
        float f[INDIM];
        #pragma unroll
        for (int k = 0; k < INDIM; ++k)
            f[k] = features[((size_t)b * INDIM + k) * LSEQ + t];

        float proj[HIDN];
        #pragma unroll 1
        for (int m = 0; m < HIDN; ++m) {
            double sA = 0.0, sB = 0.0, sC = 0.0, sD = 0.0;
            #pragma unroll
            for (int k = 0; k < INDIM; k += 4) {
                sA += (double)proj_W[m * INDIM + k + 0] * (double)f[k + 0];
                sB += (double)proj_W[m * INDIM + k + 1] * (double)f[k + 1];
                sC += (double)proj_W[m * INDIM + k + 2] * (double)f[k + 2];
                sD += (double)proj_W[m * INDIM + k + 3] * (double)f[k + 3];
            }
            proj[m] = (float)(((double)proj_b[m] + sA + sB) + (sC + sD));
        }

        const float* Wih = d ? Wih_b : Wih_f;
        const float* bs  = bias2 + d * NGATE;
        float2* out2 = (float2*)(gx + (((size_t)(d * BATCH + b) * chunkT + tt) << 7));
        #pragma unroll 1
        for (int kq = 0; kq < HIDN; ++kq) {
            const float* Wi = Wih + (kq)      * HIDN;
            const float* Wf = Wih + (kq + 32) * HIDN;
            const float* Wg = Wih + (kq + 64) * HIDN;
            const float* Wo = Wih + (kq + 96) * HIDN;
            double si_e = 0, si_o = 0, sf_e = 0, sf_o = 0;
            double sg_e = 0, sg_o = 0, so_e = 0, so_o = 0;
            #pragma unroll
            for (int m = 0; m < HIDN; m += 2) {
                double pe = (double)proj[m], po = (double)proj[m + 1];
                si_e += (double)Wi[m] * pe;  si_o += (double)Wi[m + 1] * po;
                sf_e += (double)Wf[m] * pe;  sf_o += (double)Wf[m + 1] * po;
                sg_e += (double)Wg[m] * pe;  sg_o += (double)Wg[m + 1] * po;
                so_e += (double)Wo[m] * pe;  so_o += (double)Wo[m + 1] * po;
            }
            float2 vif, vgo;
            vif.x = (float)(((double)bs[kq]      + si_e) + si_o);
            vif.y = (float)(((double)bs[kq + 32] + sf_e) + sf_o);
            vgo.x = (float)(((double)bs[kq + 64] + sg_e) + sg_o);
            vgo.y = (float)(((double)bs[kq + 96] + so_e) + so_o);
            out2[kq]      = vif;
            out2[32 + kq] = vgo;
        }
    }
}

__global__ __launch_bounds__(256) void k_gx(
    const float* __restrict__ features, const float* __restrict__ proj_W,
    const float* __restrict__ proj_b, const float* __restrict__ Wih_f,
    const float* __restrict__ Wih_b, const float* __restrict__ bias2,
    float* __restrict__ gx, int chunkT, int s0)
{
    gx_device(features, proj_W, proj_b, Wih_f, Wih_b, bias2, gx,
              chunkT, s0, blockIdx.x, threadIdx.x);
}

// ---------------------------------------------------------------------------
// Lane-packed dual-pair step. Pair A state on lanes 0-31, pair B on 32-63.
// B reads its gx/Whh rows with lane^32 so its (i,f) gates land on hi lanes.
// Front (matvec + gate activations) is per-pair (bitwise = R13); the back-end
// (cn -> exp -> div -> tanh -> hn, store, hsum) is ONE shared packed stream.
// Swaps: value-select FIRST (cndmask, full exec), then ONE unconditional
// permlane32_swap, then select the return half — never under divergence.
// ---------------------------------------------------------------------------
template<int HSTEP>
__device__ __forceinline__ void step_pk(
    float2 cvA, float2 cvB, int idx,
    v2f (&wvA)[HIDN], v2f (&wvB)[HIDN],
    float qqA, float nnA, float aaA,
    float qqB, float nnB, float aaB,
    bool lo,
    float& hcur, float& c_pk, double& hs, float* hp)
{
    v2f accA = v2f{cvA.x, cvA.y};
    v2f accB = v2f{cvB.x, cvB.y};
    #pragma unroll
    for (int m = 0; m < HIDN; ++m) {
        float hmA = readlane_f(hcur, m);        // A's h lives on lanes 0-31
        float hmB = readlane_f(hcur, m + 32);   // B's h lives on lanes 32-63
        accA = __builtin_elementwise_fma(wvA[m], v2f{hmA, hmA}, accA);
        accB = __builtin_elementwise_fma(wvB[m], v2f{hmB, hmB}, accB);
    }
    // front activations (per pair, bitwise = R13)
    float e0A = __expf(qqA * accA.x);
    float e0B = __expf(qqB * accB.x);
    float a0A = nnA / (1.f + e0A) + aaA;
    float a0B = nnB / (1.f + e0B) + aaB;
    float e1A = __expf(-accA.y);
    float e1B = __expf(-accB.y);
    float a1A = 1.f / (1.f + e1A);
    float a1B = 1.f / (1.f + e1B);
    // pack: lo lanes = pair A, hi lanes = pair B.
    // vg: lo = tanh(g_B), hi = tanh(g_A)  ->  halfswap gives each lane the
    // OTHER half: lo <- tanh(g_A), hi <- tanh(g_B). Same for vo with sig(o).
    float vg  = lo ? a0B : a0A;
    float vo  = lo ? a1B : a1A;
    float xg  = halfswap(vg, lo);
    float xo  = halfswap(vo, lo);
    float a0p = lo ? a0A : a0B;                    // sig(i)
    float a1p = lo ? a1A : a1B;                    // sig(f)
    // shared packed back-end (numpy rounding pattern, bitwise = R13 per lane)
    float cn = __fadd_rn(__fmul_rn(a1p, c_pk), __fmul_rn(a0p, xg));
    float ec = __expf(-2.f * cn);
    float tc = 2.f / (1.f + ec) - 1.f;
    float hn = __fmul_rn(xo, tc);
    c_pk = cn; hcur = hn;
    hs += (double)hn;
    hp[idx * HSTEP * HIDN] = hn;                   // all 64 lanes real stores
}

// Dual-pair recurrence loop; direction templated (immediate store offsets).
// Depth-4 ping-pong prefetch per pair (keeps VGPR need ~200 incl. 128 weights).
template<int HSTEP>
__device__ __forceinline__ void rec_body2(
    const float2* __restrict__ gqA, const float2* __restrict__ gqB,
    float* __restrict__ hp,
    v2f (&wvA)[HIDN], v2f (&wvB)[HIDN],
    float qqA, float nnA, float aaA,
    float qqB, float nnB, float aaB,
    bool lo, int lane, int lxB,
    float& hcur, float& c_pk, double& hs,
    int chunkT)
{
    float2 PA[4], QA[4], PB[4], QB[4];
    #pragma unroll
    for (int u = 0; u < 4; ++u) {
        PA[u] = gqA[u * 64 + lane];
        PB[u] = gqB[u * 64 + lxB];
    }

    #pragma unroll 1
    for (int tt = 0; tt < chunkT; tt += 8) {
        #pragma unroll
        for (int u = 0; u < 4; ++u) {
            QA[u] = gqA[(u + 4) * 64 + lane];
            QB[u] = gqB[(u + 4) * 64 + lxB];
            step_pk<HSTEP>(PA[u], PB[u], u, wvA, wvB,
                           qqA, nnA, aaA, qqB, nnB, aaB, lo, hcur, c_pk, hs, hp);
        }
        #pragma unroll
        for (int u = 0; u < 4; ++u) {
            PA[u] = gqA[(u + 8) * 64 + lane];    // pad covers tail overread
            PB[u] = gqB[(u + 8) * 64 + lxB];
            step_pk<HSTEP>(QA[u], QB[u], 4 + u, wvA, wvB,
                           qqA, nnA, aaA, qqB, nnB, aaB, lo, hcur, c_pk, hs, hp);
        }
        gqA += 8 * 64; gqB += 8 * 64;
        hp  += 8 * HSTEP * HIDN;
    }
}

// ---------------------------------------------------------------------------
// k_fused: blocks 0..31 = lane-packed dual-pair recurrence (1 wave each;
// pairs (d,b) and (d,b+16)); blocks 32+ = gx for the NEXT chunk into gxDst.
// waves_per_eu(1,1): the MAX=1 is what frees the scheduler from its occupancy
// target so the 128 weight VGPRs stay resident (R8 precedent: 48->132; the
// single-arg form (1) only sets MIN and the scheduler kept sinking the
// weight loads into the loop -> VGPR stuck at 104-112 through R13-R16).
// ---------------------------------------------------------------------------
__global__ __launch_bounds__(256)
__attribute__((amdgpu_waves_per_eu(1, 1)))
void k_fused(
    const float* __restrict__ gxSrc,   // [2][B][chunkT][64 float2] (+pad)
    float* __restrict__ gxDst,
    const float* __restrict__ features, const float* __restrict__ proj_W,
    const float* __restrict__ proj_b, const float* __restrict__ Wih_f,
    const float* __restrict__ Wih_b, const float* __restrict__ bias2,
    const float* __restrict__ Whh_f,   // [128][32]
    const float* __restrict__ Whh_b,
    float* __restrict__ hbuf,          // [2][B][L][32] fp32
    float* __restrict__ state,         // [2][B][2][32]  (h then c)
    double* __restrict__ hsum,         // [2][B][32] fp64
    int chunkT, int s0_rec, int s0_gx)
{
    if (blockIdx.x >= 32) {
        gx_device(features, proj_W, proj_b, Wih_f, Wih_b, bias2, gxDst,
                  chunkT, s0_gx, blockIdx.x - 32, threadIdx.x);
        return;
    }
    if (threadIdx.x >= 64) return;
    __builtin_amdgcn_s_setprio(1);      // favor rec wave over co-resident gx waves

    const int blk  = blockIdx.x;        // [0,32): d = blk>>4, bA = blk&15
    const int d    = blk >> 4;
    const int wgA  = d * 32 + (blk & 15);
    const int wgB  = wgA + 16;
    const int lane = threadIdx.x;
    const int lxB  = lane ^ 32;
    const int k    = lane & 31;
    const int half = lane >> 5;
    const bool lo  = (half == 0);

    // A rows: lo=(i,f), hi=(g,o).  B rows flipped: lo=(g,o), hi=(i,f).
    const int r0A = k + (half << 6),       r1A = r0A + 32;
    const int r0B = k + ((half ^ 1) << 6), r1B = r0B + 32;

    // a0: A: sig(i) lo | tanh(g) hi.  B: tanh(g) lo | sig(i) hi.
    const float qqA = half ? -2.f : -1.f;
    const float nnA = half ?  2.f :  1.f;
    const float aaA = half ? -1.f :  0.f;
    const float qqB = half ? -1.f : -2.f;
    const float nnB = half ?  1.f :  2.f;
    const float aaB = half ?  0.f : -1.f;

    const float* whh = d ? Whh_b : Whh_f;
    v2f wvA[HIDN], wvB[HIDN];
    #pragma unroll
    for (int q = 0; q < 8; ++q) {
        float4 a0v = *reinterpret_cast<const float4*>(whh + r0A * HIDN + 4 * q);
        float4 a1v = *reinterpret_cast<const float4*>(whh + r1A * HIDN + 4 * q);
        float4 b0v = *reinterpret_cast<const float4*>(whh + r0B * HIDN + 4 * q);
        float4 b1v = *reinterpret_cast<const float4*>(whh + r1B * HIDN + 4 * q);
        wvA[4 * q + 0] = v2f{a0v.x, a1v.x}; wvA[4 * q + 1] = v2f{a0v.y, a1v.y};
        wvA[4 * q + 2] = v2f{a0v.z, a1v.z}; wvA[4 * q + 3] = v2f{a0v.w, a1v.w};
        wvB[4 * q + 0] = v2f{b0v.x, b1v.x}; wvB[4 * q + 1] = v2f{b0v.y, b1v.y};
        wvB[4 * q + 2] = v2f{b0v.z, b1v.z}; wvB[4 * q + 3] = v2f{b0v.w, b1v.w};
    }

    // packed state: lanes 0-31 = pair A, lanes 32-63 = pair B (index k each)
    float* stSel = state + ((lo ? wgA : wgB) << 6);
    float hcur = stSel[k];
    float c_pk = stSel[HIDN + k];
    double hs  = hsum[(lo ? wgA : wgB) * HIDN + k];

    const float2* gqA = reinterpret_cast<const float2*>(gxSrc) + ((size_t)wgA * chunkT << 6);
    const float2* gqB = reinterpret_cast<const float2*>(gxSrc) + ((size_t)wgB * chunkT << 6);
    const int t0 = d ? (LSEQ - 1 - s0_rec) : s0_rec;
    float* hp = hbuf + (((size_t)(lo ? wgA : wgB) * LSEQ + t0) << 5) + k;

    if (d == 0)
        rec_body2<+1>(gqA, gqB, hp, wvA, wvB, qqA, nnA, aaA, qqB, nnB, aaB,
                      lo, lane, lxB, hcur, c_pk, hs, chunkT);
    else
        rec_body2<-1>(gqA, gqB, hp, wvA, wvB, qqA, nnA, aaA, qqB, nnB, aaB,
                      lo, lane, lxB, hcur, c_pk, hs, chunkT);

    stSel[k] = hcur;
    stSel[HIDN + k] = c_pk;
    hsum[(lo ? wgA : wgB) * HIDN + k] = hs;
}

// ---------------------------------------------------------------------------
// k_probs: per (b,t): h1 = relu([hf,hb] @ bc_W1.T + b1); p = sig(h1.bc_W2+b2);
//          edge *1.2; clip [0,1]. fp64 dots, 2-way chain split.
// ---------------------------------------------------------------------------
__global__ __launch_bounds__(256) void k_probs(
    const float* __restrict__ hbuf,            // [2][B][L][32] fp32
    const float* __restrict__ bcW1, const float* __restrict__ bcb1,
    const float* __restrict__ bcW2, const float* __restrict__ bcb2,
    float* __restrict__ out)
{
    int idx = blockIdx.x * 256 + threadIdx.x;   // b*L + t
    int t = idx & (LSEQ - 1);
    int b = idx >> 14;

    float h[64];
    const float* pf = hbuf + (((size_t)b * LSEQ + t) << 5);
    const float* pb = hbuf + (((size_t)(BATCH + b) * LSEQ + t) << 5);
    #pragma unroll
    for (int q = 0; q < 8; ++q) {
        float4 v = reinterpret_cast<const float4*>(pf)[q];
        h[q * 4] = v.x; h[q * 4 + 1] = v.y; h[q * 4 + 2] = v.z; h[q * 4 + 3] = v.w;
    }
    #pragma unroll
    for (int q = 0; q < 8; ++q) {
        float4 v = reinterpret_cast<const float4*>(pb)[q];
        h[32 + q * 4] = v.x; h[32 + q * 4 + 1] = v.y; h[32 + q * 4 + 2] = v.z; h[32 + q * 4 + 3] = v.w;
    }

    double a2 = (double)bcb2[0];
    #pragma unroll 1
    for (int m = 0; m < 32; ++m) {
        double ae = 0.0, ao = 0.0;
        #pragma unroll
        for (int kk = 0; kk < 64; kk += 2) {
            ae += (double)bcW1[m * 64 + kk]     * (double)h[kk];
            ao += (double)bcW1[m * 64 + kk + 1] * (double)h[kk + 1];
        }
        float af = fmaxf((float)(((double)bcb1[m] + ae) + ao), 0.f);
        a2 += (double)bcW2[m] * (double)af;
    }
    float p = fsig((float)a2);
    if (t == 0 || t == LSEQ - 1) p = __fmul_rn(p, 1.2f);
    p = fminf(fmaxf(p, 0.f), 1.f);
    out[idx] = p;
}

__global__ __launch_bounds__(256) void k_adj(
    const float* __restrict__ probs, float* __restrict__ adj)
{
    int idx = blockIdx.x * 256 + threadIdx.x;
    int t = idx & (LSEQ - 1);
    float a = 0.f;
    if (t > 0 && t < LSEQ - 1) {
        float p = probs[idx], pm = probs[idx - 1], pp = probs[idx + 1];
        float left = __fadd_rn(p, -pm), right = __fadd_rn(p, -pp);
        float al = fabsf(left), ar = fabsf(right);
        if (left < 0.f && al > ar)       a = -1.f;
        else if (right < 0.f && ar > al) a =  1.f;
    }
    adj[idx] = a;
}

__global__ __launch_bounds__(64) void k_realp(
    const double* __restrict__ hsum, const float* __restrict__ rcW,
    const float* __restrict__ rcb, float* __restrict__ out)
{
    int b = threadIdx.x;
    if (b < BATCH) {
        const double invL = 1.0 / (double)LSEQ;
        double acc = (double)rcb[0];
        #pragma unroll
        for (int kk = 0; kk < 32; ++kk) {
            acc += hsum[b * 32 + kk] * invL * (double)rcW[kk];
            acc += hsum[(BATCH + b) * 32 + kk] * invL * (double)rcW[32 + kk];
        }
        out[b] = fsig((float)acc);
    }
}

// ---------------------------------------------------------------------------
extern "C" void kernel_launch(void* const* d_in, const int* in_sizes, int n_in,
                              void* d_out, int out_size, void* d_ws, size_t ws_size,
                              hipStream_t stream)
{
    (void)in_sizes; (void)n_in; (void)out_size;
    const float* features = (const float*)d_in[0];
    const float* proj_W   = (const float*)d_in[1];
    const float* proj_b   = (const float*)d_in[2];
    const float* Wih_f    = (const float*)d_in[3];
    const float* Whh_f    = (const float*)d_in[4];
    const float* bih_f    = (const float*)d_in[5];
    const float* bhh_f    = (const float*)d_in[6];
    const float* Wih_b    = (const float*)d_in[7];
    const float* Whh_b    = (const float*)d_in[8];
    const float* bih_b    = (const float*)d_in[9];
    const float* bhh_b    = (const float*)d_in[10];
    const float* bcW1     = (const float*)d_in[11];
    const float* bcb1     = (const float*)d_in[12];
    const float* bcW2     = (const float*)d_in[13];
    const float* bcb2     = (const float*)d_in[14];
    const float* rcW      = (const float*)d_in[15];
    const float* rcb      = (const float*)d_in[16];

    char* ws = (char*)d_ws;
    float*  bias2 = (float*)(ws + 65536);              // 1 KiB
    double* hsum  = (double*)(ws + 66560);             // 16 KiB (fp64)
    float*  state = (float*)(ws + 82944);              // 16 KiB
    const size_t HBYTES = (size_t)2 * BATCH * LSEQ * HIDN * sizeof(float); // 128 MiB
    float* hbuf = (float*)(ws + (1u << 20));
    const size_t GXOFF = (1u << 20) + HBYTES;

    // chunkT selection: largest pow2 whose DOUBLE-buffered gx fits (pipelined
    // mode); else single-buffer serial fallback. Deterministic from ws_size.
    auto gxstride = [](int c) { return (size_t)c * 32768 + 16384; };
    int chunkT = LSEQ;
    bool dbuf = true;
    while (chunkT > 256 && GXOFF + 2 * gxstride(chunkT) > ws_size) chunkT >>= 1;
    if (GXOFF + 2 * gxstride(chunkT) > ws_size) {
        dbuf = false;
        chunkT = LSEQ;
        while (chunkT > 256 && GXOFF + gxstride(chunkT) > ws_size) chunkT >>= 1;
    }
    const int nch = LSEQ / chunkT;
    float* gx0 = (float*)(ws + GXOFF);
    float* gx1 = dbuf ? (float*)(ws + GXOFF + gxstride(chunkT)) : gx0;

    float* outp = (float*)d_out;
    const int BL = BATCH * LSEQ;
    const int gxblocks = BATCH * (chunkT >> 8);

    k_prep<<<16, 256, 0, stream>>>(bih_f, bhh_f, bih_b, bhh_b, bias2, hsum, state);
    k_gx<<<gxblocks, 256, 0, stream>>>(features, proj_W, proj_b,
                                       Wih_f, Wih_b, bias2, gx0, chunkT, 0);
    for (int c = 0; c < nch; ++c) {
        float* src = (c & 1) ? gx1 : gx0;
        float* dst = (c & 1) ? gx0 : gx1;
        if (dbuf) {
            bool more = (c + 1 < nch);
            k_fused<<<32 + (more ? gxblocks : 0), 256, 0, stream>>>(
                src, dst, features, proj_W, proj_b, Wih_f, Wih_b, bias2,
                Whh_f, Whh_b, hbuf, state, hsum,
                chunkT, c * chunkT, (c + 1) * chunkT);
        } else {
            if (c > 0)
                k_gx<<<gxblocks, 256, 0, stream>>>(features, proj_W, proj_b,
                                                   Wih_f, Wih_b, bias2, gx0,
                                                   chunkT, c * chunkT);
            k_fused<<<32, 256, 0, stream>>>(
                gx0, gx0, features, proj_W, proj_b, Wih_f, Wih_b, bias2,
                Whh_f, Whh_b, hbuf, state, hsum,
                chunkT, c * chunkT, 0);
        }
    }
    k_probs<<<BL / 256, 256, 0, stream>>>(hbuf, bcW1, bcb1, bcW2, bcb2, outp);
    k_adj<<<BL / 256, 256, 0, stream>>>(outp, outp + BL);
    k_realp<<<1, 64, 0, stream>>>(hsum, rcW, rcb, outp + 2 * BL);
}

// Round 18
// 4734.513 us; speedup vs baseline: 1.8094x; 1.7549x over previous
//
#include <hip/hip_runtime.h>
#include <hip/hip_bf16.h>
#include <stdint.h>

#define LSEQ   16384
#define BATCH  32
#define HIDN   32
#define NGATE  128   // 4*HIDN
#define INDIM  64

typedef float v2f __attribute__((ext_vector_type(2)));
typedef int   v2i __attribute__((ext_vector_type(2)));

// libm-accurate sigmoid for the small output kernels.
__device__ __forceinline__ float fsig(float x) { return 1.f / (1.f + expf(-x)); }

__device__ __forceinline__ float readlane_f(float v, int l) {
    return __uint_as_float((unsigned)__builtin_amdgcn_readlane((int)__float_as_uint(v), l));
}

// lane l<32 gets x from lane l+32; lanes >=32 get their own x (unused there).
// v_permlane32_swap_b32 semantics: vdst[32:63] <-> vsrc[0:31]. With both
// operands = x, ret.y (new src) has: lanes 0-31 = hi-half value; 32-63 = own.
// Called unconditionally in uniform control flow (R15 lesson: never under
// divergence — fi=false leaves cross-half reads unfetched).
__device__ __forceinline__ float xswap32(float x) {
    v2i r = __builtin_amdgcn_permlane32_swap(
        (int)__float_as_uint(x), (int)__float_as_uint(x), false, false);
    return __uint_as_float((unsigned)r.y);
}

// ---------------------------------------------------------------------------
// k_prep: bias2[d][j] = bih[j] + bhh[j]; zero hsum (fp64) and h/c state.
// ---------------------------------------------------------------------------
__global__ __launch_bounds__(256) void k_prep(
    const float* __restrict__ bih_f, const float* __restrict__ bhh_f,
    const float* __restrict__ bih_b, const float* __restrict__ bhh_b,
    float* __restrict__ bias2, double* __restrict__ hsum, float* __restrict__ state)
{
    int gid = blockIdx.x * 256 + threadIdx.x;   // [0, 4096)
    if (gid < 256) {
        int dd = gid >> 7, jj = gid & 127;
        float bi = dd ? bih_b[jj] : bih_f[jj];
        float bh = dd ? bhh_b[jj] : bhh_f[jj];
        bias2[gid] = __fadd_rn(bi, bh);
    }
    if (gid < 2 * BATCH * HIDN) hsum[gid] = 0.0;
    state[gid] = 0.f;   // 4096 = 2*B*2*32
}

// ---------------------------------------------------------------------------
// gx device body: exact (fp64) dots rounded to fp32 where numpy rounds.
// BIT-IDENTICAL to the R8-passing k_gx. Store layout:
//   out2[k]    = (i_k, f_k)     k in [0,32)
//   out2[32+k] = (g_k, o_k)
// ---------------------------------------------------------------------------
__device__ __forceinline__ void gx_device(
    const float* __restrict__ features,  // [B][64][L]
    const float* __restrict__ proj_W,    // [32][64]
    const float* __restrict__ proj_b,    // [32]
    const float* __restrict__ Wih_f,     // [128][32]
    const float* __restrict__ Wih_b,
    const float* __restrict__ bias2,     // [2][128]
    float* __restrict__ gx,
    int chunkT, int s0, int blk, int tid)
{
    int tilesPerB = chunkT >> 8;
    int b  = blk / tilesPerB;
    int tt = (blk % tilesPerB) * 256 + tid;
    int s  = s0 + tt;

    #pragma unroll 1
    for (int d = 0; d < 2; ++d) {
        int t = d ? (LSEQ - 1 - s) : s;
        float f[INDIM];
        #pragma unroll
        for (int k = 0; k < INDIM; ++k)
            f[k] = features[((size_t)b * INDIM + k) * LSEQ + t];

        float proj[HIDN];
        #pragma unroll 1
        for (int m = 0; m < HIDN; ++m) {
            double sA = 0.0, sB = 0.0, sC = 0.0, sD = 0.0;
            #pragma unroll
            for (int k = 0; k < INDIM; k += 4) {
                sA += (double)proj_W[m * INDIM + k + 0] * (double)f[k + 0];
                sB += (double)proj_W[m * INDIM + k + 1] * (double)f[k + 1];
                sC += (double)proj_W[m * INDIM + k + 2] * (double)f[k + 2];
                sD += (double)proj_W[m * INDIM + k + 3] * (double)f[k + 3];
            }
            proj[m] = (float)(((double)proj_b[m] + sA + sB) + (sC + sD));
        }

        const float* Wih = d ? Wih_b : Wih_f;
        const float* bs  = bias2 + d * NGATE;
        float2* out2 = (float2*)(gx + (((size_t)(d * BATCH + b) * chunkT + tt) << 7));
        #pragma unroll 1
        for (int kq = 0; kq < HIDN; ++kq) {
            const float* Wi = Wih + (kq)      * HIDN;
            const float* Wf = Wih + (kq + 32) * HIDN;
            const float* Wg = Wih + (kq + 64) * HIDN;
            const float* Wo = Wih + (kq + 96) * HIDN;
            double si_e = 0, si_o = 0, sf_e = 0, sf_o = 0;
            double sg_e = 0, sg_o = 0, so_e = 0, so_o = 0;
            #pragma unroll
            for (int m = 0; m < HIDN; m += 2) {
                double pe = (double)proj[m], po = (double)proj[m + 1];
                si_e += (double)Wi[m] * pe;  si_o += (double)Wi[m + 1] * po;
                sf_e += (double)Wf[m] * pe;  sf_o += (double)Wf[m + 1] * po;
                sg_e += (double)Wg[m] * pe;  sg_o += (double)Wg[m + 1] * po;
                so_e += (double)Wo[m] * pe;  so_o += (double)Wo[m + 1] * po;
            }
            float2 vif, vgo;
            vif.x = (float)(((double)bs[kq]      + si_e) + si_o);
            vif.y = (float)(((double)bs[kq + 32] + sf_e) + sf_o);
            vgo.x = (float)(((double)bs[kq + 64] + sg_e) + sg_o);
            vgo.y = (float)(((double)bs[kq + 96] + so_e) + so_o);
            out2[kq]      = vif;
            out2[32 + kq] = vgo;
        }
    }
}

__global__ __launch_bounds__(256) void k_gx(
    const float* __restrict__ features, const float* __restrict__ proj_W,
    const float* __restrict__ proj_b, const float* __restrict__ Wih_f,
    const float* __restrict__ Wih_b, const float* __restrict__ bias2,
    float* __restrict__ gx, int chunkT, int s0)
{
    gx_device(features, proj_W, proj_b, Wih_f, Wih_b, bias2, gx,
              chunkT, s0, blockIdx.x, threadIdx.x);
}

// ---------------------------------------------------------------------------
// One LSTM step — numerics BITWISE identical to R8/R10/R13: sequential m=0..31
// pk-fma chain (per-half IEEE fma), __expf + IEEE div activations, numpy c/h
// rounding. R13 exact form: v_pk_fma_f32 with SGPR op_sel broadcast +
// permlane32_swap transport + unconditional trash store.
// ---------------------------------------------------------------------------
#define LSTM_STEP(CURV, IDX) do {                                             \
    v2f acc = v2f{(CURV).x, (CURV).y};                                        \
    _Pragma("unroll")                                                         \
    for (int m = 0; m < HIDN; ++m) {                                          \
        float hm = readlane_f(hcur, m);                                       \
        acc = __builtin_elementwise_fma(wv[m], v2f{hm, hm}, acc);             \
    }                                                                         \
    float g0 = acc.x, g1 = acc.y;                                             \
    float e0 = __expf(qA * g0);                                               \
    float a0 = numA / (1.f + e0) + addA;                                      \
    float e1 = __expf(-g1);                                                   \
    float a1 = 1.f / (1.f + e1);                                              \
    float xg = xswap32(a0);                                                   \
    float xo = xswap32(a1);                                                   \
    float p1 = __fmul_rn(a1, c_my);                                           \
    float p2 = __fmul_rn(a0, xg);                                             \
    float cn = __fadd_rn(p1, p2);                                             \
    float ec = __expf(-2.f * cn);                                             \
    float tc = 2.f / (1.f + ec) - 1.f;                                        \
    float hn = __fmul_rn(xo, tc);                                             \
    c_my = cn; hcur = hn;                                                     \
    hs_my += (double)hn;                                                      \
    hp[(IDX) * HSTEP * HIDN] = hn;                                            \
} while (0)

// Main recurrence loop; direction templated so h-store offsets are immediates.
// Ping-pong A/B prefetch (distance 8, no rotation copies). hp for lanes>=32
// points at a fixed trash line and does not advance.
template<int HSTEP>
__device__ __forceinline__ void rec_body(
    const float2* __restrict__ gq2, float* __restrict__ hp,
    v2f (&wv)[HIDN], float qA, float numA, float addA,
    float& hcur, float& c_my, double& hs_my,
    int chunkT, int lane)
{
    const ptrdiff_t adv = (lane < HIDN) ? (ptrdiff_t)16 * HSTEP * HIDN : 0;

    float2 A[8], B[8];
    #pragma unroll
    for (int u = 0; u < 8; ++u) A[u] = gq2[u * 64 + lane];

    #pragma unroll 1
    for (int tt = 0; tt < chunkT; tt += 16) {
        #pragma unroll
        for (int u = 0; u < 8; ++u) {
            B[u] = gq2[(u + 8) * 64 + lane];        // rows tt+8..tt+15
            LSTM_STEP(A[u], u);
        }
        #pragma unroll
        for (int u = 0; u < 8; ++u) {
            A[u] = gq2[(u + 16) * 64 + lane];       // rows tt+16..tt+23 (pad at tail)
            LSTM_STEP(B[u], 8 + u);
        }
        gq2 += 16 * 64;
        hp  += adv;
    }
}

// ---------------------------------------------------------------------------
// k_fused: blocks 0..63 = recurrence (1 wave, threads 0-63, setprio 1) reading
// gxSrc; blocks 64+ = gx for the NEXT chunk into gxDst (disjoint buffer, no
// sync needed). gx values bit-identical to standalone k_gx (same device fn).
// waves_per_eu(1): R13 configuration — single-pair needs ~104 VGPR and the
// 64 weight VGPRs stay resident at that pressure (R13 measured 644 cy/step).
// ---------------------------------------------------------------------------
__global__ __launch_bounds__(256)
__attribute__((amdgpu_waves_per_eu(1)))
void k_fused(
    const float* __restrict__ gxSrc,   // [2][B][chunkT][64 float2] (+pad)
    float* __restrict__ gxDst,
    const float* __restrict__ features, const float* __restrict__ proj_W,
    const float* __restrict__ proj_b, const float* __restrict__ Wih_f,
    const float* __restrict__ Wih_b, const float* __restrict__ bias2,
    const float* __restrict__ Whh_f,   // [128][32]
    const float* __restrict__ Whh_b,
    float* __restrict__ hbuf,          // [2][B][L][32] fp32
    float* __restrict__ state,         // [2][B][2][32]  (h then c)
    double* __restrict__ hsum,         // [2][B][32] fp64
    float* __restrict__ trash,         // 16 KiB dead zone (hi-lane stores)
    int chunkT, int s0_rec, int s0_gx)
{
    if (blockIdx.x >= 64) {
        gx_device(features, proj_W, proj_b, Wih_f, Wih_b, bias2, gxDst,
                  chunkT, s0_gx, blockIdx.x - 64, threadIdx.x);
        return;
    }
    if (threadIdx.x >= 64) return;
    __builtin_amdgcn_s_setprio(1);      // favor rec wave over co-resident gx waves

    const int wg   = blockIdx.x;        // d*32 + b
    const int d    = wg >> 5;
    const int lane = threadIdx.x;
    const int k    = lane & 31;
    const int half = lane >> 5;         // 0: i/f rows, 1: g/o rows
    const int r0   = k + (half << 6);   // i or g row
    const int r1   = r0 + 32;           // f or o row

    // a0 activation: lo lanes sigmoid(i), hi lanes tanh(g)
    const float qA   = half ? -2.f : -1.f;
    const float numA = half ?  2.f :  1.f;
    const float addA = half ? -1.f :  0.f;

    const float* whh = d ? Whh_b : Whh_f;
    // wv[m] = (Whh[r0][m], Whh[r1][m]) — loaded via float4, paired in regs
    v2f wv[HIDN];
    #pragma unroll
    for (int q = 0; q < 8; ++q) {
        float4 a = *reinterpret_cast<const float4*>(whh + r0 * HIDN + 4 * q);
        float4 b = *reinterpret_cast<const float4*>(whh + r1 * HIDN + 4 * q);
        wv[4 * q + 0] = v2f{a.x, b.x};
        wv[4 * q + 1] = v2f{a.y, b.y};
        wv[4 * q + 2] = v2f{a.z, b.z};
        wv[4 * q + 3] = v2f{a.w, b.w};
    }

    float* st = state + (wg << 6);
    float hcur = st[k];
    float c_my = st[HIDN + k];
    double hs_my = (lane < HIDN) ? hsum[wg * HIDN + lane] : 0.0;

    const float2* gq2 = reinterpret_cast<const float2*>(gxSrc) + ((size_t)wg * chunkT << 6);
    const int t0 = d ? (LSEQ - 1 - s0_rec) : s0_rec;
    float* hpreal = hbuf + (((size_t)wg * LSEQ + t0) << 5) + k;
    float* hp = (lane < HIDN) ? hpreal : (trash + 2048 + lane);  // center of 16 KiB zone

    if (d == 0)
        rec_body<+1>(gq2, hp, wv, qA, numA, addA, hcur, c_my, hs_my, chunkT, lane);
    else
        rec_body<-1>(gq2, hp, wv, qA, numA, addA, hcur, c_my, hs_my, chunkT, lane);

    if (lane < HIDN) {
        st[lane] = hcur;
        st[HIDN + lane] = c_my;
        hsum[wg * HIDN + lane] = hs_my;
    }
}

// ---------------------------------------------------------------------------
// k_probs: per (b,t): h1 = relu([hf,hb] @ bc_W1.T + b1); p = sig(h1.bc_W2+b2);
//          edge *1.2; clip [0,1]. fp64 dots, 2-way chain split.
// ---------------------------------------------------------------------------
__global__ __launch_bounds__(256) void k_probs(
    const float* __restrict__ hbuf,            // [2][B][L][32] fp32
    const float* __restrict__ bcW1, const float* __restrict__ bcb1,
    const float* __restrict__ bcW2, const float* __restrict__ bcb2,
    float* __restrict__ out)
{
    int idx = blockIdx.x * 256 + threadIdx.x;   // b*L + t
    int t = idx & (LSEQ - 1);
    int b = idx >> 14;

    float h[64];
    const float* pf = hbuf + (((size_t)b * LSEQ + t) << 5);
    const float* pb = hbuf + (((size_t)(BATCH + b) * LSEQ + t) << 5);
    #pragma unroll
    for (int q = 0; q < 8; ++q) {
        float4 v = reinterpret_cast<const float4*>(pf)[q];
        h[q * 4] = v.x; h[q * 4 + 1] = v.y; h[q * 4 + 2] = v.z; h[q * 4 + 3] = v.w;
    }
    #pragma unroll
    for (int q = 0; q < 8; ++q) {
        float4 v = reinterpret_cast<const float4*>(pb)[q];
        h[32 + q * 4] = v.x; h[32 + q * 4 + 1] = v.y; h[32 + q * 4 + 2] = v.z; h[32 + q * 4 + 3] = v.w;
    }

    double a2 = (double)bcb2[0];
    #pragma unroll 1
    for (int m = 0; m < 32; ++m) {
        double ae = 0.0, ao = 0.0;
        #pragma unroll
        for (int kk = 0; kk < 64; kk += 2) {
            ae += (double)bcW1[m * 64 + kk]     * (double)h[kk];
            ao += (double)bcW1[m * 64 + kk + 1] * (double)h[kk + 1];
        }
        float af = fmaxf((float)(((double)bcb1[m] + ae) + ao), 0.f);
        a2 += (double)bcW2[m] * (double)af;
    }
    float p = fsig((float)a2);
    if (t == 0 || t == LSEQ - 1) p = __fmul_rn(p, 1.2f);
    p = fminf(fmaxf(p, 0.f), 1.f);
    out[idx] = p;
}

__global__ __launch_bounds__(256) void k_adj(
    const float* __restrict__ probs, float* __restrict__ adj)
{
    int idx = blockIdx.x * 256 + threadIdx.x;
    int t = idx & (LSEQ - 1);
    float a = 0.f;
    if (t > 0 && t < LSEQ - 1) {
        float p = probs[idx], pm = probs[idx - 1], pp = probs[idx + 1];
        float left = __fadd_rn(p, -pm), right = __fadd_rn(p, -pp);
        float al = fabsf(left), ar = fabsf(right);
        if (left < 0.f && al > ar)       a = -1.f;
        else if (right < 0.f && ar > al) a =  1.f;
    }
    adj[idx] = a;
}

__global__ __launch_bounds__(64) void k_realp(
    const double* __restrict__ hsum, const float* __restrict__ rcW,
    const float* __restrict__ rcb, float* __restrict__ out)
{
    int b = threadIdx.x;
    if (b < BATCH) {
        const double invL = 1.0 / (double)LSEQ;
        double acc = (double)rcb[0];
        #pragma unroll
        for (int kk = 0; kk < 32; ++kk) {
            acc += hsum[b * 32 + kk] * invL * (double)rcW[kk];
            acc += hsum[(BATCH + b) * 32 + kk] * invL * (double)rcW[32 + kk];
        }
        out[b] = fsig((float)acc);
    }
}

// ---------------------------------------------------------------------------
extern "C" void kernel_launch(void* const* d_in, const int* in_sizes, int n_in,
                              void* d_out, int out_size, void* d_ws, size_t ws_size,
                              hipStream_t stream)
{
    (void)in_sizes; (void)n_in; (void)out_size;
    const float* features = (const float*)d_in[0];
    const float* proj_W   = (const float*)d_in[1];
    const float* proj_b   = (const float*)d_in[2];
    const float* Wih_f    = (const float*)d_in[3];
    const float* Whh_f    = (const float*)d_in[4];
    const float* bih_f    = (const float*)d_in[5];
    const float* bhh_f    = (const float*)d_in[6];
    const float* Wih_b    = (const float*)d_in[7];
    const float* Whh_b    = (const float*)d_in[8];
    const float* bih_b    = (const float*)d_in[9];
    const float* bhh_b    = (const float*)d_in[10];
    const float* bcW1     = (const float*)d_in[11];
    const float* bcb1     = (const float*)d_in[12];
    const float* bcW2     = (const float*)d_in[13];
    const float* bcb2     = (const float*)d_in[14];
    const float* rcW      = (const float*)d_in[15];
    const float* rcb      = (const float*)d_in[16];

    char* ws = (char*)d_ws;
    float*  bias2 = (float*)(ws + 65536);              // 1 KiB
    double* hsum  = (double*)(ws + 66560);             // 16 KiB (fp64)
    float*  state = (float*)(ws + 82944);              // 16 KiB
    float*  trash = (float*)(ws + 102400);             // 16 KiB dead zone
    const size_t HBYTES = (size_t)2 * BATCH * LSEQ * HIDN * sizeof(float); // 128 MiB
    float* hbuf = (float*)(ws + (1u << 20));
    const size_t GXOFF = (1u << 20) + HBYTES;

    // chunkT selection: largest pow2 whose DOUBLE-buffered gx fits (pipelined
    // mode); else single-buffer serial fallback. Deterministic from ws_size.
    auto gxstride = [](int c) { return (size_t)c * 32768 + 16384; };
    int chunkT = LSEQ;
    bool dbuf = true;
    while (chunkT > 256 && GXOFF + 2 * gxstride(chunkT) > ws_size) chunkT >>= 1;
    if (GXOFF + 2 * gxstride(chunkT) > ws_size) {
        dbuf = false;
        chunkT = LSEQ;
        while (chunkT > 256 && GXOFF + gxstride(chunkT) > ws_size) chunkT >>= 1;
    }
    const int nch = LSEQ / chunkT;
    float* gx0 = (float*)(ws + GXOFF);
    float* gx1 = dbuf ? (float*)(ws + GXOFF + gxstride(chunkT)) : gx0;

    float* outp = (float*)d_out;
    const int BL = BATCH * LSEQ;
    const int gxblocks = BATCH * (chunkT >> 8);

    k_prep<<<16, 256, 0, stream>>>(bih_f, bhh_f, bih_b, bhh_b, bias2, hsum, state);
    k_gx<<<gxblocks, 256, 0, stream>>>(features, proj_W, proj_b,
                                       Wih_f, Wih_b, bias2, gx0, chunkT, 0);
    for (int c = 0; c < nch; ++c) {
        float* src = (c & 1) ? gx1 : gx0;
        float* dst = (c & 1) ? gx0 : gx1;
        if (dbuf) {
            bool more = (c + 1 < nch);
            k_fused<<<64 + (more ? gxblocks : 0), 256, 0, stream>>>(
                src, dst, features, proj_W, proj_b, Wih_f, Wih_b, bias2,
                Whh_f, Whh_b, hbuf, state, hsum, trash,
                chunkT, c * chunkT, (c + 1) * chunkT);
        } else {
            if (c > 0)
                k_gx<<<gxblocks, 256, 0, stream>>>(features, proj_W, proj_b,
                                                   Wih_f, Wih_b, bias2, gx0,
                                                   chunkT, c * chunkT);
            k_fused<<<64, 256, 0, stream>>>(
                gx0, gx0, features, proj_W, proj_b, Wih_f, Wih_b, bias2,
                Whh_f, Whh_b, hbuf, state, hsum, trash,
                chunkT, c * chunkT, 0);
        }
    }
    k_probs<<<BL / 256, 256, 0, stream>>>(hbuf, bcW1, bcb1, bcW2, bcb2, outp);
    k_adj<<<BL / 256, 256, 0, stream>>>(outp, outp + BL);
    k_realp<<<1, 64, 0, stream>>>(hsum, rcW, rcb, outp + 2 * BL);
}